// Round 5
// baseline (1579.812 us; speedup 1.0000x reference)
//
#include <hip/hip_runtime.h>

// ============================ CALIBRATION ROUND ============================
// v5 = v4b (byte-identical data path) + ~300 us per-block s_memrealtime spin
// AFTER s_waitcnt vmcnt(0). Purpose: four structurally different kernels
// (v0/v2/v3/v4) all timed identically (~1065-1092 headline), and our kernel
// has never appeared in the top-5 counter rows (poison fills ~697 us hide it).
// This probe (a) lifts our dispatch above the fills so we finally SEE its
// WRITE_SIZE / FETCH_SIZE / dur, (b) disambiguates whether the timed window
// contains the kernel once (T~=370, real 2.1x gap) or effectively twice
// (T~=185 ~= write roofline 174 us, i.e. already done).
//   expected: dispatch ~785 us & headline ~2250 -> T=185, at roofline
//         or: dispatch ~975 us & headline ~1670 -> T=375, read its W/F sizes.
// vmcnt(0) before the spin ensures store drain is NOT hidden by the sleep.
// ===========================================================================

#define NROWS 2048
#define ROWF 65
#define CHUNK_ROWS 16
#define CHUNK_FLOATS (CHUNK_ROWS * ROWF)   // 1040 floats = 4160 B per wave
#define TILES_PER_BLOCK 16
#define NBLOCKS ((NROWS * NROWS / 64) / TILES_PER_BLOCK)  // 4096

// ~300 us at s_memrealtime's fixed ~100 MHz clock
#define CALIB_TICKS 30000ull

typedef float f32x4 __attribute__((ext_vector_type(4)));

static __device__ __forceinline__ void nt_store4(float4* p, float4 v) {
    f32x4 nv = { v.x, v.y, v.z, v.w };
    __builtin_nontemporal_store(nv, (f32x4*)p);   // global_store_dwordx4 ... nt
}

__global__ __launch_bounds__(256) void expand_calib(
    const float* __restrict__ emb,   // [2048*32]
    const float* __restrict__ sw,    // [2048]
    float4* __restrict__ out)        // flat output as float4
{
    __shared__ __align__(16) float lds[4][CHUNK_FLOATS];  // 16,640 B

    const unsigned tid  = threadIdx.x;
    const unsigned w    = tid >> 6;
    const unsigned lane = tid & 63u;
    const unsigned t0   = blockIdx.x * TILES_PER_BLOCK;
    const unsigned i    = t0 >> 5;               // constant per block
    const unsigned rb   = w * CHUNK_ROWS;        // this wave's rows in a tile

    float* __restrict__ my = lds[w];

    const unsigned jrA = lane >> 3;          // 0..7
    const unsigned jrB = jrA + 8u;           // 8..15
    const unsigned cc  = (lane & 7u) * 4u;   // 0,4,...,28

    // ---- I-part: cols 0..31 of all 16 rows, written once ----
    {
        const float4 vi = *(const float4*)(emb + i * 32u + cc);
        float* dA = my + jrA * ROWF + cc;
        float* dB = my + jrB * ROWF + cc;
        dA[0] = vi.x; dA[1] = vi.y; dA[2] = vi.z; dA[3] = vi.w;
        dB[0] = vi.x; dB[1] = vi.y; dB[2] = vi.z; dB[3] = vi.w;
    }

    // ---- prologue: stage tile t0's J-strip ----
    float4 ja, jb;
    float  s = 0.0f;
    {
        const unsigned j0  = (t0 & 31u) * 64u + rb;
        const float4*  src = (const float4*)(emb + j0 * 32u);
        ja = src[lane];
        jb = src[lane + 64u];
        if (lane < CHUNK_ROWS) s = sw[j0 + lane];
    }
    {
        float* dA = my + jrA * ROWF + 32u + cc;
        dA[0] = ja.x; dA[1] = ja.y; dA[2] = ja.z; dA[3] = ja.w;
        float* dB = my + jrB * ROWF + 32u + cc;
        dB[0] = jb.x; dB[1] = jb.y; dB[2] = jb.z; dB[3] = jb.w;
        if (lane < CHUNK_ROWS) my[lane * ROWF + 64u] = s;
    }

#pragma unroll 1
    for (unsigned kk = 0; kk < TILES_PER_BLOCK; ++kk) {
        const unsigned tile = t0 + kk;

        if (kk + 1u < TILES_PER_BLOCK) {
            const unsigned j0  = ((tile + 1u) & 31u) * 64u + rb;
            const float4*  src = (const float4*)(emb + j0 * 32u);
            ja = src[lane];
            jb = src[lane + 64u];
            if (lane < CHUNK_ROWS) s = sw[j0 + lane];
        }

        asm volatile("s_waitcnt lgkmcnt(0)" ::: "memory");
        __builtin_amdgcn_sched_barrier(0);

        const float4* __restrict__ b4 = (const float4*)my;
        float4 r0 = b4[lane];
        float4 r1 = b4[lane + 64u];
        float4 r2 = b4[lane + 128u];
        float4 r3 = b4[lane + 192u];
        float4 r4 = {0.f, 0.f, 0.f, 0.f};
        if (lane < 4u) r4 = b4[lane + 256u];

        asm volatile("s_waitcnt lgkmcnt(0)" ::: "memory");
        __builtin_amdgcn_sched_barrier(0);

        const unsigned base = tile * 1040u + w * 260u;   // f4 units
        nt_store4(&out[base + lane],        r0);
        nt_store4(&out[base + lane + 64u],  r1);
        nt_store4(&out[base + lane + 128u], r2);
        nt_store4(&out[base + lane + 192u], r3);
        if (lane < 4u) nt_store4(&out[base + lane + 256u], r4);

        if (kk + 1u < TILES_PER_BLOCK) {
            float* dA = my + jrA * ROWF + 32u + cc;
            dA[0] = ja.x; dA[1] = ja.y; dA[2] = ja.z; dA[3] = ja.w;
            float* dB = my + jrB * ROWF + 32u + cc;
            dB[0] = jb.x; dB[1] = jb.y; dB[2] = jb.z; dB[3] = jb.w;
            if (lane < CHUNK_ROWS) my[lane * ROWF + 64u] = s;
        }
        __builtin_amdgcn_sched_barrier(0);
    }

    // ---- calibration tail: drain our stores, THEN spin ~300 us ----
    asm volatile("s_waitcnt vmcnt(0)" ::: "memory");
    __builtin_amdgcn_sched_barrier(0);
    {
        const unsigned long long t0c = __builtin_amdgcn_s_memrealtime();
        while (__builtin_amdgcn_s_memrealtime() - t0c < CALIB_TICKS) {
            __builtin_amdgcn_s_sleep(8);
        }
    }
}

extern "C" void kernel_launch(void* const* d_in, const int* in_sizes, int n_in,
                              void* d_out, int out_size, void* d_ws, size_t ws_size,
                              hipStream_t stream) {
    const float* emb = (const float*)d_in[0];   // [2048, 32] f32
    const float* sw  = (const float*)d_in[1];   // [2048] f32
    float4* out      = (float4*)d_out;

    expand_calib<<<dim3(NBLOCKS), dim3(256), 0, stream>>>(emb, sw, out);
}

// Round 6
// 1074.511 us; speedup vs baseline: 1.4703x; 1.4703x over previous
//
#include <hip/hip_runtime.h>
#include <stdint.h>

// n=2048, f=32. Output row r = [emb[i](32) | emb[j](32) | sw[j]], i=r>>11,
// j=r&2047. Output 1.09 GB, write-BW bound. Calibration (v5) closed the books:
// kernel was ~232 us vs 177 us roofline; traffic clean (WRITE=1.083GB,
// FETCH~0). Limiter by arithmetic: LDS ISSUE — 9 scalar ds_write_b32 + 5
// ds_read_b128 = ~112 LDS-cyc per 1040 B stored = 9.3 B/cy < 10.2 needed.
//
// v6: eliminate LDS writes from the wave-issue path.
//  - I-half (cols 0..31, all rows) is loop-invariant: written ONCE per wave.
//  - Pure-J 16B chunks (fully inside a J-segment) are CONTIGUOUS in emb ->
//    staged via global_load_lds_dwordx4 (linear LDS dest, per-lane global
//    src; masked lanes skip). Zero ds_write instructions for the bulk.
//  - Leftovers (sw + row-straddle J floats) = EXACTLY 64 floats per wave
//    image -> one full-wave global_load_dword + ONE ds_write_b32 patch.
//  Per-tile LDS issue: 5 b128 reads + 1 b32 write ~ 66 cyc/1040 B = 15.8 B/cy
//  ceiling (was 9.3). Staging moves to VMEM (L1/L2-hot, ample headroom).
//
// Wave-private 4160-B image, no barriers; vmcnt(0) per tile (TLP covers:
// 32 waves/CU x 1040 B / ~800 cy >> 10.2 B/cy target).

#define NROWS 2048
#define TILES_PER_BLOCK 16
#define NBLOCKS ((NROWS * NROWS / 64) / TILES_PER_BLOCK)  // 4096

typedef float f32x4_t __attribute__((ext_vector_type(4)));
typedef __attribute__((address_space(1))) const unsigned int GU32;
typedef __attribute__((address_space(3))) unsigned int LU32;

static __device__ __forceinline__ void nt_store4(float4* p, float4 v) {
    f32x4_t nv = { v.x, v.y, v.z, v.w };
    __builtin_nontemporal_store(nv, (f32x4_t*)p);
}

__global__ __launch_bounds__(256) void expand_glds(
    const float* __restrict__ emb,   // [2048*32]
    const float* __restrict__ sw,    // [2048]
    float4* __restrict__ out)
{
    __shared__ __align__(16) float lds[4][1040];   // 16,640 B -> 8 blk/CU

    const unsigned tid  = threadIdx.x;
    const unsigned w    = tid >> 6;
    const unsigned lane = tid & 63u;
    const unsigned t0   = blockIdx.x * TILES_PER_BLOCK;
    const unsigned i    = t0 >> 5;                 // constant per block
    float* __restrict__ my = lds[w];

    // ---- init (tile-invariant): chunk classification for glds ----
    // chunk k of 260: floats 4k..4k+3 of the 16x65 image; row r=4k/65,
    // col c=4k-65r. Pure-J iff 32<=c<=60 (4 floats inside one J-segment);
    // src is then emb[j0+r][c-32..c-29], contiguous.
    unsigned off_m[5]; bool pure_m[5];
#pragma unroll
    for (int m = 0; m < 5; ++m) {
        const unsigned k = (unsigned)m * 64u + lane;
        const unsigned f = 4u * k;
        const unsigned r = f / 65u;
        const unsigned c = f - 65u * r;
        pure_m[m] = (k < 260u) && (c >= 32u) && (c <= 60u);
        off_m[m]  = r * 128u + (c - 32u) * 4u;   // bytes into the j-strip
    }

    // ---- init: patch assignment — 64 leftover floats, one per lane ----
    // Per row r (b=r%4): boundary J at cols 32..35-b-1 (4-b floats, b>=1),
    // sw-side J at cols 64-b..63 (b floats), sw at col 64. Total per 4 rows
    // = 16 -> 64 per image = one patch/lane.
    unsigned prow, pcol; bool psw;
    {
        const unsigned g = lane >> 4, l = lane & 15u;
        if (l == 0u) { prow = 4u * g; pcol = 64u; psw = true; }
        else {
            const unsigned q = l - 1u, rr = q / 5u, wi = q - 5u * rr;
            prow = 4u * g + 1u + rr;
            const unsigned b = prow & 3u;          // 1..3
            if (wi < 4u - b)      { pcol = 32u + wi;                   psw = false; }
            else if (wi < 4u)     { pcol = (64u - b) + (wi - (4u - b)); psw = false; }
            else                  { pcol = 64u;                         psw = true;  }
        }
    }
    const unsigned patch_ldsoff = prow * 65u + pcol;

    // ---- prologue: I-half (cols 0..31, all 16 rows) — once per wave ----
    {
        const unsigned jrA = lane >> 3, jrB = jrA + 8u, cc = (lane & 7u) * 4u;
        const float4 vi = *(const float4*)(emb + i * 32u + cc);
        float* dA = my + jrA * 65u + cc;
        float* dB = my + jrB * 65u + cc;
        dA[0]=vi.x; dA[1]=vi.y; dA[2]=vi.z; dA[3]=vi.w;
        dB[0]=vi.x; dB[1]=vi.y; dB[2]=vi.z; dB[3]=vi.w;
    }

    // issue all staging loads for 'tile': 5 masked global_load_lds (pure-J
    // chunks) + one full-wave patch-value load. Returns the patch value.
    auto stage = [&](unsigned tile) -> float {
        const unsigned jb = (tile & 31u) * 64u + w * 16u;   // never wraps
        const char* embj = (const char*)emb + (size_t)jb * 128u;
#pragma unroll
        for (int m = 0; m < 5; ++m) {
            if (pure_m[m]) {
                __builtin_amdgcn_global_load_lds(
                    (GU32*)(embj + off_m[m]),
                    (LU32*)(my + (unsigned)m * 256u), 16, 0, 0);
            }
        }
        const float* ps = psw ? (sw + jb + prow)
                              : (emb + (size_t)(jb + prow) * 32u + (pcol - 32u));
        return *ps;
    };

    // ---- stage tile 0 ----
    float pv = stage(t0);
    asm volatile("s_waitcnt vmcnt(0)" ::: "memory");
    __builtin_amdgcn_sched_barrier(0);
    my[patch_ldsoff] = pv;          // completes tile-0 image (DS in-order)

#pragma unroll 1
    for (unsigned kk = 0; kk < TILES_PER_BLOCK; ++kk) {
        const unsigned tile = t0 + kk;

        // drain current image to regs (patch write retires first: DS in-order)
        const float4* __restrict__ b4 = (const float4*)my;
        float4 r0 = b4[lane];
        float4 r1 = b4[lane + 64u];
        float4 r2 = b4[lane + 128u];
        float4 r3 = b4[lane + 192u];
        float4 r4 = {0.f, 0.f, 0.f, 0.f};
        if (lane < 4u) r4 = b4[lane + 256u];

        // all reads retired -> image buffer is free for next tile's loads
        asm volatile("s_waitcnt lgkmcnt(0)" ::: "memory");
        __builtin_amdgcn_sched_barrier(0);

        float pvn = 0.0f;
        if (kk + 1u < TILES_PER_BLOCK) pvn = stage(tile + 1u);
        __builtin_amdgcn_sched_barrier(0);

        const unsigned base = tile * 1040u + w * 260u;   // f4 units
        nt_store4(&out[base + lane],        r0);
        nt_store4(&out[base + lane + 64u],  r1);
        nt_store4(&out[base + lane + 128u], r2);
        nt_store4(&out[base + lane + 192u], r3);
        if (lane < 4u) nt_store4(&out[base + lane + 256u], r4);
        __builtin_amdgcn_sched_barrier(0);

        if (kk + 1u < TILES_PER_BLOCK) {
            // wait loads landed (also drains stores — safe; TLP covers it)
            asm volatile("s_waitcnt vmcnt(0)" ::: "memory");
            __builtin_amdgcn_sched_barrier(0);
            my[patch_ldsoff] = pvn;     // one ds_write_b32 finishes staging
        }
    }
}

extern "C" void kernel_launch(void* const* d_in, const int* in_sizes, int n_in,
                              void* d_out, int out_size, void* d_ws, size_t ws_size,
                              hipStream_t stream) {
    const float* emb = (const float*)d_in[0];   // [2048, 32] f32
    const float* sw  = (const float*)d_in[1];   // [2048] f32
    float4* out      = (float4*)d_out;

    expand_glds<<<dim3(NBLOCKS), dim3(256), 0, stream>>>(emb, sw, out);
}